// Round 18
// baseline (158.959 us; speedup 1.0000x reference)
//
#include <hip/hip_runtime.h>
#include <hip/hip_bf16.h>

// ---------------------------------------------------------------------------
// MultiHeadAttention forward, MI355X/gfx950.
// prep(weights+bias only) -> merged GEMM QKV (A = f32 inputs, converted
// in-kernel via reg-staging) -> flash attention (r15) -> GEMM O
// Round 18: the X f32->bf16 convert pass is FUSED into the QKV GEMM:
// per step, A f32 loads issue early (fly under MFMA), cvt_pk + ds_write
// after compute into the same bf16 LDS layout (reads unchanged); barrier
// gains lgkmcnt(0) (ds_writes are lgkm-tracked). Saves ~112MB of prep
// traffic at the cost of +37.5MB f32 A reads in the GEMM.
// ---------------------------------------------------------------------------

typedef short bf16x8 __attribute__((ext_vector_type(8)));
typedef short bf16x4 __attribute__((ext_vector_type(4)));
typedef float f32x4 __attribute__((ext_vector_type(4)));
typedef float f32x16 __attribute__((ext_vector_type(16)));
typedef int i32x4 __attribute__((ext_vector_type(4)));
typedef unsigned short u16;
typedef unsigned short u16x8 __attribute__((ext_vector_type(8)));
typedef unsigned short u16x4 __attribute__((ext_vector_type(4)));

#define MFMA16(a, b, c) __builtin_amdgcn_mfma_f32_16x16x32_bf16((a), (b), (c), 0, 0, 0)
#define MFMA32(a, b, c) __builtin_amdgcn_mfma_f32_32x32x16_bf16((a), (b), (c), 0, 0, 0)
#define GLD16(gp, lp)                                                     \
  __builtin_amdgcn_global_load_lds(                                       \
      (const __attribute__((address_space(1))) void*)(gp),                \
      (__attribute__((address_space(3))) void*)(lp), 16, 0, 0)

#define WAITVM_BAR(N) asm volatile("s_waitcnt vmcnt(" #N ")\ns_barrier" ::: "memory")
#define BAR() asm volatile("s_barrier" ::: "memory")
#define LGKM_BAR() asm volatile("s_waitcnt lgkmcnt(0)\ns_barrier" ::: "memory")
#define WAITALL_BAR() \
  asm volatile("s_waitcnt vmcnt(0) lgkmcnt(0)\ns_barrier" ::: "memory")

#if __has_builtin(__builtin_amdgcn_exp2f)
#define EXP2(x) __builtin_amdgcn_exp2f(x)
#else
#define EXP2(x) exp2f(x)
#endif

__device__ __forceinline__ u16 f2bf(float f) {
  union { float f; unsigned u; } v; v.f = f;
  return (u16)((v.u + 0x7fffu + ((v.u >> 16) & 1u)) >> 16);
}
// packed f32x2 -> bf16x2 via HIP intrinsic (compiler emits v_cvt_pk_bf16_f32)
__device__ __forceinline__ unsigned pkc(float lo, float hi) {
  __hip_bfloat162 h = __float22bfloat162_rn(float2{lo, hi});
  union { __hip_bfloat162 h; unsigned u; } c; c.h = h;
  return c.u;
}
// v_permlane32_swap_b32: post: a = [a.lo, b.lo], b = [a.hi, b.hi].
// ONLY safe when a and b are provably distinct values (round-11 lesson).
__device__ __forceinline__ void pl32swap(unsigned& a, unsigned& b) {
  asm("v_permlane32_swap_b32 %0, %1" : "+v"(a), "+v"(b));
}

// ---------------- prep: weights f32->bf16 (y<4) + bias/mask prep (y==4) ----
struct ConvDesc { const float* src; u16* dst; int n; };
struct ConvArgs { ConvDesc d[4]; };

// bias_eff layout for the 32x32 fragment: out[b][q][c*32 + hi*16 + r]
//   = mask ? bias[b][q][c*32 + (r&3) + 8*(r>>2) + 4*hi] * log2e : -inf
__device__ __forceinline__ void biasprep_body(const float* __restrict__ bias,
                                              const int* __restrict__ mask,
                                              u16* __restrict__ out, int i) {
  const int o0 = i * 16;
  const int rowg = o0 >> 11;       // b*2048 + q
  const int b = rowg >> 11;
  const int off = o0 & 2047;
  const int c = off >> 5;          // 32-kv block
  const int hi = (off >> 4) & 1;
  const float* src = bias + (size_t)rowg * 2048 + c * 32 + hi * 4;
  const int* msk = mask + b * 2048 + c * 32 + hi * 4;
  u16x8 w0 = {}, w1 = {};
#pragma unroll
  for (int t = 0; t < 4; t++) {
    f32x4 v = *(const f32x4*)(src + t * 8);
    i32x4 m = *(const i32x4*)(msk + t * 8);
#pragma unroll
    for (int j = 0; j < 4; j++) {
      u16 val = (m[j] != 0) ? f2bf(v[j] * 1.44269504f) : (u16)0xFF80;
      if (t < 2) w0[t * 4 + j] = val;
      else       w1[(t - 2) * 4 + j] = val;
    }
  }
  *(u16x8*)(out + o0) = w0;
  *(u16x8*)(out + o0 + 8) = w1;
}

__global__ __launch_bounds__(256)
void k_prep(ConvArgs a, const float* __restrict__ bias,
            const int* __restrict__ mask, u16* __restrict__ bout) {
  if (blockIdx.y == 4) {
    biasprep_body(bias, mask, bout, blockIdx.x * 256 + threadIdx.x);
    return;
  }
  ConvDesc cd = a.d[blockIdx.y];
  int i = (blockIdx.x * 256 + threadIdx.x) * 8;
  if (i >= cd.n) return;
  const float4* s = (const float4*)(cd.src + i);
  float4 f0 = s[0], f1 = s[1];
  u16x8 o;
  o[0] = f2bf(f0.x); o[1] = f2bf(f0.y); o[2] = f2bf(f0.z); o[3] = f2bf(f0.w);
  o[4] = f2bf(f1.x); o[5] = f2bf(f1.y); o[6] = f2bf(f1.z); o[7] = f2bf(f1.w);
  *(u16x8*)(cd.dst + i) = o;
}

// ---------------- bf16 GEMM body: C = (A[M,K] * B[N,K]^T + bias)*oscale ----
// AF32: A is f32 in global; staged via regs (loads early, cvt+ds_write after
// compute) into the SAME bf16 LDS layout. Else A staged via global_load_lds.
template <int MF, bool AF32>
__device__ __forceinline__ void gemm_impl(const void* __restrict__ Ap,
                                          const u16* __restrict__ Bw,
                                          const float* __restrict__ bias,
                                          void* __restrict__ outp, int mode,
                                          float oscale) {
  __shared__ u16 As[2][MF * 1024];
  __shared__ u16 Bs[2][4096];
  const int tid = threadIdx.x;
  const int lane = tid & 63;
  const int wv = tid >> 6;
  const int wr = wv >> 1, wc = wv & 1;
  const int m0 = blockIdx.y * (MF * 32), n0 = blockIdx.x * 128;

  const u16* A16 = (const u16*)Ap;
  const float* A32 = (const float*)Ap;

  f32x4 acc[MF][4] = {};

  const int s0 = tid, s1 = 256 + tid;
  const int r0 = s0 >> 2, c0 = (s0 & 3) ^ (r0 & 3);
  const int r1 = s1 >> 2, c1 = (s1 & 3) ^ (r1 & 3);
  const u16* gA0 = A16 + (size_t)(m0 + r0) * 1024 + c0 * 8;
  const u16* gA1 = A16 + (size_t)(m0 + r1) * 1024 + c1 * 8;  // MF==4 only
  const float* fA0 = A32 + (size_t)(m0 + r0) * 1024 + c0 * 8;
  const float* fA1 = A32 + (size_t)(m0 + r1) * 1024 + c1 * 8;
  const u16* gB0 = Bw + (size_t)(n0 + r0) * 1024 + c0 * 8;
  const u16* gB1 = Bw + (size_t)(n0 + r1) * 1024 + c1 * 8;
  u16* lA0 = &As[0][(tid & ~63) * 8];
  u16* lB0 = &Bs[0][(tid & ~63) * 8];

  // prologue: stage k=0 into buf0
  if constexpr (AF32) {
    f32x4 a0 = *(const f32x4*)(fA0), a1 = *(const f32x4*)(fA0 + 4);
    f32x4 a2 = *(const f32x4*)(fA1), a3 = *(const f32x4*)(fA1 + 4);
    union { unsigned u[4]; bf16x8 v; } w0, w1;
    w0.u[0] = pkc(a0[0], a0[1]); w0.u[1] = pkc(a0[2], a0[3]);
    w0.u[2] = pkc(a1[0], a1[1]); w0.u[3] = pkc(a1[2], a1[3]);
    w1.u[0] = pkc(a2[0], a2[1]); w1.u[1] = pkc(a2[2], a2[3]);
    w1.u[2] = pkc(a3[0], a3[1]); w1.u[3] = pkc(a3[2], a3[3]);
    *(bf16x8*)((char*)&As[0][0] + tid * 16) = w0.v;
    *(bf16x8*)((char*)&As[0][0] + (256 + tid) * 16) = w1.v;
  } else {
    GLD16(gA0, lA0);
    if constexpr (MF == 4) GLD16(gA1, lA0 + 2048);
  }
  GLD16(gB0, lB0);
  GLD16(gB1, lB0 + 2048);
  WAITALL_BAR();

#define GSTEP(BUF, K0)                                                     \
  {                                                                        \
    const int nk = ((K0) + 32) & 1023;                                     \
    f32x4 av0, av1, av2, av3;                                              \
    if constexpr (AF32) { /* issue early; land under this tile's MFMAs */  \
      av0 = *(const f32x4*)(fA0 + nk);                                     \
      av1 = *(const f32x4*)(fA0 + nk + 4);                                 \
      av2 = *(const f32x4*)(fA1 + nk);                                     \
      av3 = *(const f32x4*)(fA1 + nk + 4);                                 \
    } else {                                                               \
      GLD16(gA0 + nk, lA0 + ((BUF) ^ 1) * (MF * 1024));                    \
      if constexpr (MF == 4)                                               \
        GLD16(gA1 + nk, lA0 + 2048 + ((BUF) ^ 1) * (MF * 1024));           \
    }                                                                      \
    GLD16(gB0 + nk, lB0 + ((BUF) ^ 1) * 4096);                             \
    GLD16(gB1 + nk, lB0 + 2048 + ((BUF) ^ 1) * 4096);                      \
    if constexpr (AF32) { WAITVM_BAR(6); }                                 \
    else if constexpr (MF == 4) { WAITVM_BAR(4); }                         \
    else { WAITVM_BAR(3); }                                                \
    bf16x8 af[MF], bfr[4];                                                 \
    _Pragma("unroll")                                                      \
    for (int mi = 0; mi < MF; mi++) {                                      \
      int row = wr * (MF * 16) + mi * 16 + (lane & 15);                    \
      int byt = row * 64 + (((lane >> 4) * 16) ^ ((row & 3) << 4));        \
      af[mi] = *(const bf16x8*)((const char*)&As[BUF][0] + byt);           \
    }                                                                      \
    _Pragma("unroll")                                                      \
    for (int ni = 0; ni < 4; ni++) {                                       \
      int row = wc * 64 + ni * 16 + (lane & 15);                           \
      int byt = row * 64 + (((lane >> 4) * 16) ^ ((row & 3) << 4));        \
      bfr[ni] = *(const bf16x8*)((const char*)&Bs[BUF][0] + byt);          \
    }                                                                      \
    __builtin_amdgcn_s_setprio(1);                                         \
    _Pragma("unroll")                                                      \
    for (int mi = 0; mi < MF; mi++)                                        \
      _Pragma("unroll")                                                    \
      for (int ni = 0; ni < 4; ni++)                                       \
        acc[mi][ni] = MFMA16(af[mi], bfr[ni], acc[mi][ni]);                \
    __builtin_amdgcn_s_setprio(0);                                         \
    if constexpr (AF32) { /* cvt + write A(T+1) into buf^1 */              \
      union { unsigned u[4]; bf16x8 v; } w0, w1;                           \
      w0.u[0] = pkc(av0[0], av0[1]); w0.u[1] = pkc(av0[2], av0[3]);        \
      w0.u[2] = pkc(av1[0], av1[1]); w0.u[3] = pkc(av1[2], av1[3]);        \
      w1.u[0] = pkc(av2[0], av2[1]); w1.u[1] = pkc(av2[2], av2[3]);        \
      w1.u[2] = pkc(av3[0], av3[1]); w1.u[3] = pkc(av3[2], av3[3]);        \
      *(bf16x8*)((char*)&As[(BUF) ^ 1][0] + tid * 16) = w0.v;              \
      *(bf16x8*)((char*)&As[(BUF) ^ 1][0] + (256 + tid) * 16) = w1.v;      \
      LGKM_BAR(); /* ds_writes are lgkm-tracked; s_barrier alone won't */  \
    } else {                                                               \
      BAR();                                                               \
    }                                                                      \
  }

  for (int k0 = 0; k0 < 1024; k0 += 64) {
    GSTEP(0, k0)
    GSTEP(1, k0 + 32)
  }
#undef GSTEP

#pragma unroll
  for (int ni = 0; ni < 4; ni++) {
    int n = n0 + wc * 64 + ni * 16 + (lane & 15);
    float bv = bias[n];
#pragma unroll
    for (int mi = 0; mi < MF; mi++) {
      int mb = m0 + wr * (MF * 16) + mi * 16 + (lane >> 4) * 4;
      if (mode == 2) {
        float* O = (float*)outp;
#pragma unroll
        for (int r = 0; r < 4; r++)
          O[(size_t)(mb + r) * 1024 + n] = (acc[mi][ni][r] + bv) * oscale;
      } else if (mode == 0) {
        u16* O = (u16*)outp;
        int b = mb >> 11, q = mb & 2047;
        int h = n >> 6, dk = n & 63;
        size_t base = ((size_t)(b * 16 + h) * 2048 + q) * 64 + dk;
#pragma unroll
        for (int r = 0; r < 4; r++)
          O[base + (size_t)r * 64] = f2bf((acc[mi][ni][r] + bv) * oscale);
      } else {  // mode 1: V^T [B,H,64,NK]
        u16* O = (u16*)outp;
        int b = mb >> 11, kv = mb & 2047;
        int h = n >> 6, dk = n & 63;
        u16x4 pk;
#pragma unroll
        for (int r = 0; r < 4; r++) pk[r] = f2bf((acc[mi][ni][r] + bv) * oscale);
        *(u16x4*)((u16*)O + ((size_t)((b * 16 + h) * 64 + dk)) * 2048 + kv) = pk;
      }
    }
  }
}

struct GemmDesc { const void* A; const u16* W; const float* bias; void* out;
                  int mode; float oscale; };
struct Gemm3 { GemmDesc d[3]; };

__global__ __launch_bounds__(256, 3) void k_gemm_qkv(Gemm3 g3) {
  GemmDesc gd = g3.d[blockIdx.z];
  gemm_impl<4, true>(gd.A, gd.W, gd.bias, gd.out, gd.mode, gd.oscale);
}
__global__ __launch_bounds__(256, 2)
void k_gemm_o(const u16* __restrict__ A, const u16* __restrict__ W,
              const float* __restrict__ bias, float* __restrict__ out) {
  gemm_impl<2, false>(A, W, bias, out, 2, 1.0f);
}

// ---------------- flash attention, 32x32 MFMA, KVBLK=128, no-max softmax ---
// (round-15 kernel verbatim: best measured, 59.7us)
__global__ __launch_bounds__(256, 2)
void k_attn(const u16* __restrict__ Qb, const u16* __restrict__ Kb,
            const u16* __restrict__ Vt, const u16* __restrict__ BiasE,
            u16* __restrict__ Ob) {
  __shared__ u16 Ks[2][128 * 64];
  __shared__ u16 Vs[2][64 * 128];

  const int tid = threadIdx.x, lane = tid & 63, w = tid >> 6;
  const int l31 = lane & 31, hi2 = lane >> 5;
  const int bid = blockIdx.x;
  const int xcd = bid & 7, rr = bid >> 3;
  const int qt = rr & 15;
  const int pr = xcd + 8 * (rr >> 4);   // (b,h) pair, 4 per XCD
  const int b = pr >> 4, h = pr & 15;
  const int q0 = qt * 128;
  const size_t bh = (size_t)(b * 16 + h);

  const u16* Qrow = Qb + (bh * 2048 + q0 + w * 32 + l31) * 64 + hi2 * 8;
  bf16x8 bq[4];
#pragma unroll
  for (int dc = 0; dc < 4; dc++) bq[dc] = *(const bf16x8*)(Qrow + dc * 16);

  f32x16 acc[2] = {};
  float lrun = 0.f;

  const u16* Kg = Kb + bh * 2048 * 64;
  const u16* Vg = Vt + bh * 64 * 2048;
  int rK[4], cK[4], rV[4], cV[4], ldd[4];
#pragma unroll
  for (int i = 0; i < 4; i++) {
    int s = i * 256 + tid;
    rK[i] = s >> 3; cK[i] = (s & 7) ^ (rK[i] & 7);
    rV[i] = s >> 4; cV[i] = (s & 15) ^ (rV[i] & 7);
    ldd[i] = (i * 256 + (tid & ~63)) * 8;
  }
  const int kx = (lane & 7) << 4;

  const u16* brow =
      BiasE + ((size_t)b * 2048 + q0 + w * 32 + l31) * 2048 + hi2 * 16;

#pragma unroll
  for (int i = 0; i < 4; i++)
    GLD16(Kg + (size_t)rK[i] * 64 + cK[i] * 8, &Ks[0][ldd[i]]);
#pragma unroll
  for (int i = 0; i < 4; i++)
    GLD16(Vg + (size_t)rV[i] * 2048 + cV[i] * 8, &Vs[0][ldd[i]]);
  u16x8 bb[4][2];
#pragma unroll
  for (int c = 0; c < 4; c++) {
    bb[c][0] = *(const u16x8*)(brow + c * 32);
    bb[c][1] = *(const u16x8*)(brow + c * 32 + 8);
  }

#define ATTN_STEP(BUF, T)                                                      \
  {                                                                            \
    WAITVM_BAR(0);                                                             \
    const char* kb = (const char*)&Ks[BUF][0];                                 \
    const char* vb = (const char*)&Vs[BUF][0];                                 \
    f32x16 sc[4];                                                              \
    __builtin_amdgcn_s_setprio(1);                                             \
    _Pragma("unroll")                                                          \
    for (int c = 0; c < 4; c++) {                                              \
      f32x16 z;                                                                \
      _Pragma("unroll")                                                        \
      for (int r = 0; r < 8; r++)                                              \
        z[r] = __uint_as_float((unsigned)bb[c][0][r] << 16);                   \
      _Pragma("unroll")                                                        \
      for (int r = 0; r < 8; r++)                                              \
        z[8 + r] = __uint_as_float((unsigned)bb[c][1][r] << 16);               \
      const int rowb = (c * 32 + l31) * 128;                                   \
      _Pragma("unroll")                                                        \
      for (int dc = 0; dc < 4; dc++) {                                         \
        bf16x8 ak =                                                            \
            *(const bf16x8*)(kb + rowb + ((dc * 32 + hi2 * 16) ^ kx));         \
        z = MFMA32(ak, bq[dc], z);                                             \
      }                                                                        \
      sc[c] = z;                                                               \
    }                                                                          \
    __builtin_amdgcn_s_setprio(0);                                             \
    const int nkv = (((T) + 1) & 15) * 128;                                    \
    _Pragma("unroll")                                                          \
    for (int i = 0; i < 4; i++)                                                \
      GLD16(Kg + (size_t)(nkv + rK[i]) * 64 + cK[i] * 8,                       \
            &Ks[(BUF) ^ 1][ldd[i]]);                                           \
    _Pragma("unroll")                                                          \
    for (int i = 0; i < 4; i++)                                                \
      GLD16(Vg + (size_t)rV[i] * 2048 + nkv + cV[i] * 8,                       \
            &Vs[(BUF) ^ 1][ldd[i]]);                                           \
    _Pragma("unroll")                                                          \
    for (int c = 0; c < 4; c++) {                                              \
      bb[c][0] = *(const u16x8*)(brow + nkv + c * 32);                         \
      bb[c][1] = *(const u16x8*)(brow + nkv + c * 32 + 8);                     \
    }                                                                          \
    _Pragma("unroll")                                                          \
    for (int c = 0; c < 4; c++)                                                \
      _Pragma("unroll")                                                        \
      for (int r = 0; r < 16; r++) sc[c][r] = EXP2(sc[c][r]);                  \
    float cs[4];                                                               \
    _Pragma("unroll")                                                          \
    for (int c = 0; c < 4; c++) {                                              \
      float s8[8];                                                             \
      _Pragma("unroll")                                                        \
      for (int r = 0; r < 8; r++) s8[r] = sc[c][r] + sc[c][r + 8];             \
      float s4[4];                                                             \
      _Pragma("unroll")                                                        \
      for (int r = 0; r < 4; r++) s4[r] = s8[r] + s8[r + 4];                   \
      cs[c] = (s4[0] + s4[1]) + (s4[2] + s4[3]);                               \
    }                                                                          \
    lrun += (cs[0] + cs[1]) + (cs[2] + cs[3]);                                 \
    __builtin_amdgcn_s_setprio(1);                                             \
    _Pragma("unroll")                                                          \
    for (int c = 0; c < 4; c++) {                                              \
      unsigned a0 = pkc(sc[c][0], sc[c][1]), b0 = pkc(sc[c][4], sc[c][5]);     \
      unsigned a1 = pkc(sc[c][2], sc[c][3]), b1 = pkc(sc[c][6], sc[c][7]);     \
      unsigned e0 = pkc(sc[c][8], sc[c][9]), f0 = pkc(sc[c][12], sc[c][13]);   \
      unsigned e1 = pkc(sc[c][10], sc[c][11]), f1 = pkc(sc[c][14], sc[c][15]); \
      pl32swap(a0, b0); pl32swap(a1, b1);                                      \
      pl32swap(e0, f0); pl32swap(e1, f1);                                      \
      union { unsigned u[4]; bf16x8 v; } fe, fo;                               \
      fe.u[0] = a0; fe.u[1] = a1; fe.u[2] = b0; fe.u[3] = b1;                  \
      fo.u[0] = e0; fo.u[1] = e1; fo.u[2] = f0; fo.u[3] = f1;                  \
      _Pragma("unroll")                                                        \
      for (int ds = 0; ds < 2; ds++) {                                         \
        const int vrow = (ds * 32 + l31) * 256;                                \
        bf16x8 ve =                                                            \
            *(const bf16x8*)(vb + vrow + (((c * 4 + hi2) * 16) ^ kx));         \
        acc[ds] = MFMA32(ve, fe.v, acc[ds]);                                   \
        bf16x8 vo =                                                            \
            *(const bf16x8*)(vb + vrow + (((c * 4 + 2 + hi2) * 16) ^ kx));     \
        acc[ds] = MFMA32(vo, fo.v, acc[ds]);                                   \
      }                                                                        \
    }                                                                          \
    __builtin_amdgcn_s_setprio(0);                                             \
  }

  for (int t = 0; t < 16; t += 2) {
    ATTN_STEP(0, t)
    ATTN_STEP(1, t + 1)
  }
#undef ATTN_STEP

  lrun += __shfl_xor(lrun, 32, 64);
  float linv = 1.0f / lrun;
  const size_t obase =
      ((size_t)b * 2048 + q0 + w * 32 + l31) * 1024 + h * 64 + hi2 * 4;
#pragma unroll
  for (int ds = 0; ds < 2; ds++)
#pragma unroll
    for (int t = 0; t < 4; t++) {
      u16x4 pk;
#pragma unroll
      for (int j = 0; j < 4; j++) pk[j] = f2bf(acc[ds][t * 4 + j] * linv);
      *(u16x4*)(Ob + obase + ds * 32 + t * 8) = pk;
    }
}

// ---------------------------------------------------------------------------
extern "C" void kernel_launch(void* const* d_in, const int* in_sizes, int n_in,
                              void* d_out, int out_size, void* d_ws,
                              size_t ws_size, hipStream_t stream) {
  (void)in_sizes; (void)n_in; (void)out_size; (void)ws_size;
  const float* q_in = (const float*)d_in[0];
  const float* k_in = (const float*)d_in[1];
  const float* v_in = (const float*)d_in[2];
  const int* mask = (const int*)d_in[3];
  const float* attn_bias = (const float*)d_in[4];
  const float* w_q = (const float*)d_in[5];
  const float* b_q = (const float*)d_in[6];
  const float* w_k = (const float*)d_in[7];
  const float* b_k = (const float*)d_in[8];
  const float* w_v = (const float*)d_in[9];
  const float* b_v = (const float*)d_in[10];
  const float* w_o = (const float*)d_in[11];
  const float* b_o = (const float*)d_in[12];

  const size_t MB = 1u << 20;
  char* ws = (char*)d_ws;
  u16* BiasE = (u16*)(ws + 0 * MB);   // 16.8 MB (X buffers no longer exist)
  u16* WQ = (u16*)(ws + 24 * MB);
  u16* WK = (u16*)(ws + 26 * MB);
  u16* WV = (u16*)(ws + 28 * MB);
  u16* WO = (u16*)(ws + 30 * MB);
  u16* Qb = (u16*)(ws + 32 * MB);
  u16* Kb = (u16*)(ws + 40 * MB);
  u16* Vt = (u16*)(ws + 48 * MB);
  u16* Ob = (u16*)(ws + 56 * MB);

  ConvArgs ca;
  ca.d[0] = {w_q, WQ, 1024 * 1024};
  ca.d[1] = {w_k, WK, 1024 * 1024};
  ca.d[2] = {w_v, WV, 1024 * 1024};
  ca.d[3] = {w_o, WO, 1024 * 1024};
  k_prep<<<dim3(2048, 5), 256, 0, stream>>>(ca, attn_bias, mask, BiasE);

  const float QSCALE = 0.125f * 1.44269504f;
  Gemm3 g3;
  g3.d[0] = {q_in, WQ, b_q, (void*)Qb, 0, QSCALE};
  g3.d[1] = {k_in, WK, b_k, (void*)Kb, 0, 1.0f};
  g3.d[2] = {v_in, WV, b_v, (void*)Vt, 1, 1.0f};
  k_gemm_qkv<<<dim3(8, 32, 3), 256, 0, stream>>>(g3);

  k_attn<<<512, 256, 0, stream>>>(Qb, Kb, Vt, BiasE, Ob);

  k_gemm_o<<<dim3(8, 64), 256, 0, stream>>>(Ob, WO, b_o, (float*)d_out);
}

// Round 19
// 136.274 us; speedup vs baseline: 1.1665x; 1.1665x over previous
//
#include <hip/hip_runtime.h>
#include <hip/hip_bf16.h>

// ---------------------------------------------------------------------------
// MultiHeadAttention forward, MI355X/gfx950.
// prep(convert+biasmask) -> merged GEMM QKV -> flash attention (r15) -> GEMM O
// Round 19: r18's fusion reverted (A f32 re-read x8 across N-tiles made the
// GEMM HBM-bound: FETCH 206MB, 82us). Kept the r18 diagnosis: same-A-panel
// blocks scatter across XCDs. Fix: 1-D grid + bijective remap so each XCD
// owns whole (y,z) panels (8 N-tile blocks sharing an A panel co-resident
// on one XCD -> A L2-served). Attn/prep = r15 verbatim (best: 141.6us).
// ---------------------------------------------------------------------------

typedef short bf16x8 __attribute__((ext_vector_type(8)));
typedef short bf16x4 __attribute__((ext_vector_type(4)));
typedef float f32x4 __attribute__((ext_vector_type(4)));
typedef float f32x16 __attribute__((ext_vector_type(16)));
typedef int i32x4 __attribute__((ext_vector_type(4)));
typedef unsigned short u16;
typedef unsigned short u16x8 __attribute__((ext_vector_type(8)));
typedef unsigned short u16x4 __attribute__((ext_vector_type(4)));

#define MFMA16(a, b, c) __builtin_amdgcn_mfma_f32_16x16x32_bf16((a), (b), (c), 0, 0, 0)
#define MFMA32(a, b, c) __builtin_amdgcn_mfma_f32_32x32x16_bf16((a), (b), (c), 0, 0, 0)
#define GLD16(gp, lp)                                                     \
  __builtin_amdgcn_global_load_lds(                                       \
      (const __attribute__((address_space(1))) void*)(gp),                \
      (__attribute__((address_space(3))) void*)(lp), 16, 0, 0)

#define WAITVM_BAR(N) asm volatile("s_waitcnt vmcnt(" #N ")\ns_barrier" ::: "memory")
#define BAR() asm volatile("s_barrier" ::: "memory")

#if __has_builtin(__builtin_amdgcn_exp2f)
#define EXP2(x) __builtin_amdgcn_exp2f(x)
#else
#define EXP2(x) exp2f(x)
#endif

__device__ __forceinline__ u16 f2bf(float f) {
  union { float f; unsigned u; } v; v.f = f;
  return (u16)((v.u + 0x7fffu + ((v.u >> 16) & 1u)) >> 16);
}
// packed f32x2 -> bf16x2 via HIP intrinsic (compiler emits v_cvt_pk_bf16_f32)
__device__ __forceinline__ unsigned pkc(float lo, float hi) {
  __hip_bfloat162 h = __float22bfloat162_rn(float2{lo, hi});
  union { __hip_bfloat162 h; unsigned u; } c; c.h = h;
  return c.u;
}
// v_permlane32_swap_b32: post: a = [a.lo, b.lo], b = [a.hi, b.hi].
// ONLY safe when a and b are provably distinct values (round-11 lesson).
__device__ __forceinline__ void pl32swap(unsigned& a, unsigned& b) {
  asm("v_permlane32_swap_b32 %0, %1" : "+v"(a), "+v"(b));
}

// ---------------- prep: f32->bf16 convert (y<7) + bias/mask prep (y==7) ----
struct ConvDesc { const float* src; u16* dst; int n; };
struct ConvArgs { ConvDesc d[7]; };

// bias_eff layout for the 32x32 fragment: out[b][q][c*32 + hi*16 + r]
//   = mask ? bias[b][q][c*32 + (r&3) + 8*(r>>2) + 4*hi] * log2e : -inf
__device__ __forceinline__ void biasprep_body(const float* __restrict__ bias,
                                              const int* __restrict__ mask,
                                              u16* __restrict__ out, int i) {
  const int o0 = i * 16;
  const int rowg = o0 >> 11;       // b*2048 + q
  const int b = rowg >> 11;
  const int off = o0 & 2047;
  const int c = off >> 5;          // 32-kv block
  const int hi = (off >> 4) & 1;
  const float* src = bias + (size_t)rowg * 2048 + c * 32 + hi * 4;
  const int* msk = mask + b * 2048 + c * 32 + hi * 4;
  u16x8 w0 = {}, w1 = {};
#pragma unroll
  for (int t = 0; t < 4; t++) {
    f32x4 v = *(const f32x4*)(src + t * 8);
    i32x4 m = *(const i32x4*)(msk + t * 8);
#pragma unroll
    for (int j = 0; j < 4; j++) {
      u16 val = (m[j] != 0) ? f2bf(v[j] * 1.44269504f) : (u16)0xFF80;
      if (t < 2) w0[t * 4 + j] = val;
      else       w1[(t - 2) * 4 + j] = val;
    }
  }
  *(u16x8*)(out + o0) = w0;
  *(u16x8*)(out + o0 + 8) = w1;
}

__global__ __launch_bounds__(256)
void k_prep(ConvArgs a, const float* __restrict__ bias,
            const int* __restrict__ mask, u16* __restrict__ bout) {
  if (blockIdx.y == 7) {
    biasprep_body(bias, mask, bout, blockIdx.x * 256 + threadIdx.x);
    return;
  }
  ConvDesc cd = a.d[blockIdx.y];
  int i = (blockIdx.x * 256 + threadIdx.x) * 8;
  if (i >= cd.n) return;
  const float4* s = (const float4*)(cd.src + i);
  float4 f0 = s[0], f1 = s[1];
  u16x8 o;
  o[0] = f2bf(f0.x); o[1] = f2bf(f0.y); o[2] = f2bf(f0.z); o[3] = f2bf(f0.w);
  o[4] = f2bf(f1.x); o[5] = f2bf(f1.y); o[6] = f2bf(f1.z); o[7] = f2bf(f1.w);
  *(u16x8*)(cd.dst + i) = o;
}

__global__ __launch_bounds__(256)
void k_biasprep(const float* __restrict__ bias, const int* __restrict__ mask,
                u16* __restrict__ out) {
  biasprep_body(bias, mask, out, blockIdx.x * 256 + threadIdx.x);
}

// ---------------- bf16 GEMM body: C = (A[M,K] * B[N,K]^T + bias)*oscale ----
template <int MF>
__device__ __forceinline__ void gemm_impl(const u16* __restrict__ A,
                                          const u16* __restrict__ Bw,
                                          const float* __restrict__ bias,
                                          void* __restrict__ outp, int mode,
                                          float oscale, int m0, int n0) {
  __shared__ u16 As[2][MF * 1024];
  __shared__ u16 Bs[2][4096];
  const int tid = threadIdx.x;
  const int lane = tid & 63;
  const int wv = tid >> 6;
  const int wr = wv >> 1, wc = wv & 1;

  f32x4 acc[MF][4] = {};

  const int s0 = tid, s1 = 256 + tid;
  const int r0 = s0 >> 2, c0 = (s0 & 3) ^ (r0 & 3);
  const int r1 = s1 >> 2, c1 = (s1 & 3) ^ (r1 & 3);
  const u16* gA0 = A + (size_t)(m0 + r0) * 1024 + c0 * 8;
  const u16* gA1 = A + (size_t)(m0 + r1) * 1024 + c1 * 8;  // MF==4 only
  const u16* gB0 = Bw + (size_t)(n0 + r0) * 1024 + c0 * 8;
  const u16* gB1 = Bw + (size_t)(n0 + r1) * 1024 + c1 * 8;
  u16* lA0 = &As[0][(tid & ~63) * 8];
  u16* lB0 = &Bs[0][(tid & ~63) * 8];

  GLD16(gA0, lA0);
  if constexpr (MF == 4) GLD16(gA1, lA0 + 2048);
  GLD16(gB0, lB0);
  GLD16(gB1, lB0 + 2048);
  WAITVM_BAR(0);

#define GSTEP(BUF, K0)                                                     \
  {                                                                        \
    const int nk = ((K0) + 32) & 1023;                                     \
    GLD16(gA0 + nk, lA0 + ((BUF) ^ 1) * (MF * 1024));                      \
    if constexpr (MF == 4)                                                 \
      GLD16(gA1 + nk, lA0 + 2048 + ((BUF) ^ 1) * (MF * 1024));             \
    GLD16(gB0 + nk, lB0 + ((BUF) ^ 1) * 4096);                             \
    GLD16(gB1 + nk, lB0 + 2048 + ((BUF) ^ 1) * 4096);                      \
    if constexpr (MF == 4) { WAITVM_BAR(4); } else { WAITVM_BAR(3); }      \
    bf16x8 af[MF], bfr[4];                                                 \
    _Pragma("unroll")                                                      \
    for (int mi = 0; mi < MF; mi++) {                                      \
      int row = wr * (MF * 16) + mi * 16 + (lane & 15);                    \
      int byt = row * 64 + (((lane >> 4) * 16) ^ ((row & 3) << 4));        \
      af[mi] = *(const bf16x8*)((const char*)&As[BUF][0] + byt);           \
    }                                                                      \
    _Pragma("unroll")                                                      \
    for (int ni = 0; ni < 4; ni++) {                                       \
      int row = wc * 64 + ni * 16 + (lane & 15);                           \
      int byt = row * 64 + (((lane >> 4) * 16) ^ ((row & 3) << 4));        \
      bfr[ni] = *(const bf16x8*)((const char*)&Bs[BUF][0] + byt);          \
    }                                                                      \
    __builtin_amdgcn_s_setprio(1);                                         \
    _Pragma("unroll")                                                      \
    for (int mi = 0; mi < MF; mi++)                                        \
      _Pragma("unroll")                                                    \
      for (int ni = 0; ni < 4; ni++)                                       \
        acc[mi][ni] = MFMA16(af[mi], bfr[ni], acc[mi][ni]);                \
    __builtin_amdgcn_s_setprio(0);                                         \
    BAR();                                                                 \
  }

  for (int k0 = 0; k0 < 1024; k0 += 64) {
    GSTEP(0, k0)
    GSTEP(1, k0 + 32)
  }
#undef GSTEP

#pragma unroll
  for (int ni = 0; ni < 4; ni++) {
    int n = n0 + wc * 64 + ni * 16 + (lane & 15);
    float bv = bias[n];
#pragma unroll
    for (int mi = 0; mi < MF; mi++) {
      int mb = m0 + wr * (MF * 16) + mi * 16 + (lane >> 4) * 4;
      if (mode == 2) {
        float* O = (float*)outp;
#pragma unroll
        for (int r = 0; r < 4; r++)
          O[(size_t)(mb + r) * 1024 + n] = (acc[mi][ni][r] + bv) * oscale;
      } else if (mode == 0) {
        u16* O = (u16*)outp;
        int b = mb >> 11, q = mb & 2047;
        int h = n >> 6, dk = n & 63;
        size_t base = ((size_t)(b * 16 + h) * 2048 + q) * 64 + dk;
#pragma unroll
        for (int r = 0; r < 4; r++)
          O[base + (size_t)r * 64] = f2bf((acc[mi][ni][r] + bv) * oscale);
      } else {  // mode 1: V^T [B,H,64,NK]
        u16* O = (u16*)outp;
        int b = mb >> 11, kv = mb & 2047;
        int h = n >> 6, dk = n & 63;
        u16x4 pk;
#pragma unroll
        for (int r = 0; r < 4; r++) pk[r] = f2bf((acc[mi][ni][r] + bv) * oscale);
        *(u16x4*)((u16*)O + ((size_t)((b * 16 + h) * 64 + dk)) * 2048 + kv) = pk;
      }
    }
  }
}

struct GemmDesc { const u16* A; const u16* W; const float* bias; void* out;
                  int mode; float oscale; };
struct Gemm3 { GemmDesc d[3]; };

// 768 blocks 1-D: XCD panel-grouping. xcd=bid&7; t=bid>>3: n=t&7,
// p=(t>>3)*8+xcd in 0..95 -> y=p&31, z=p>>5. The 8 blocks sharing an A
// panel (same y,z) all have bid%8==xcd -> co-resident on one XCD.
__global__ __launch_bounds__(256, 3) void k_gemm_qkv(Gemm3 g3) {
  const int bid = blockIdx.x;
  const int xcd = bid & 7, t = bid >> 3;
  const int n = t & 7;
  const int p = (t >> 3) * 8 + xcd;  // 0..95
  const int y = p & 31, z = p >> 5;
  GemmDesc gd = g3.d[z];
  gemm_impl<4>(gd.A, gd.W, gd.bias, gd.out, gd.mode, gd.oscale, y * 128,
               n * 128);
}
// 512 blocks 1-D: same scheme, 64 y-panels of BM=64.
__global__ __launch_bounds__(256, 2)
void k_gemm_o(const u16* __restrict__ A, const u16* __restrict__ W,
              const float* __restrict__ bias, float* __restrict__ out) {
  const int bid = blockIdx.x;
  const int xcd = bid & 7, t = bid >> 3;
  const int n = t & 7;
  const int y = (t >> 3) * 8 + xcd;  // 0..63
  gemm_impl<2>(A, W, bias, out, 2, 1.0f, y * 64, n * 128);
}

// ---------------- flash attention, 32x32 MFMA, KVBLK=128, no-max softmax ---
// (round-15 kernel verbatim: best measured, 59.7us)
__global__ __launch_bounds__(256, 2)
void k_attn(const u16* __restrict__ Qb, const u16* __restrict__ Kb,
            const u16* __restrict__ Vt, const u16* __restrict__ BiasE,
            u16* __restrict__ Ob) {
  __shared__ u16 Ks[2][128 * 64];
  __shared__ u16 Vs[2][64 * 128];

  const int tid = threadIdx.x, lane = tid & 63, w = tid >> 6;
  const int l31 = lane & 31, hi2 = lane >> 5;
  const int bid = blockIdx.x;
  const int xcd = bid & 7, rr = bid >> 3;
  const int qt = rr & 15;
  const int pr = xcd + 8 * (rr >> 4);   // (b,h) pair, 4 per XCD
  const int b = pr >> 4, h = pr & 15;
  const int q0 = qt * 128;
  const size_t bh = (size_t)(b * 16 + h);

  const u16* Qrow = Qb + (bh * 2048 + q0 + w * 32 + l31) * 64 + hi2 * 8;
  bf16x8 bq[4];
#pragma unroll
  for (int dc = 0; dc < 4; dc++) bq[dc] = *(const bf16x8*)(Qrow + dc * 16);

  f32x16 acc[2] = {};
  float lrun = 0.f;

  const u16* Kg = Kb + bh * 2048 * 64;
  const u16* Vg = Vt + bh * 64 * 2048;
  int rK[4], cK[4], rV[4], cV[4], ldd[4];
#pragma unroll
  for (int i = 0; i < 4; i++) {
    int s = i * 256 + tid;
    rK[i] = s >> 3; cK[i] = (s & 7) ^ (rK[i] & 7);
    rV[i] = s >> 4; cV[i] = (s & 15) ^ (rV[i] & 7);
    ldd[i] = (i * 256 + (tid & ~63)) * 8;
  }
  const int kx = (lane & 7) << 4;

  const u16* brow =
      BiasE + ((size_t)b * 2048 + q0 + w * 32 + l31) * 2048 + hi2 * 16;

#pragma unroll
  for (int i = 0; i < 4; i++)
    GLD16(Kg + (size_t)rK[i] * 64 + cK[i] * 8, &Ks[0][ldd[i]]);
#pragma unroll
  for (int i = 0; i < 4; i++)
    GLD16(Vg + (size_t)rV[i] * 2048 + cV[i] * 8, &Vs[0][ldd[i]]);
  u16x8 bb[4][2];
#pragma unroll
  for (int c = 0; c < 4; c++) {
    bb[c][0] = *(const u16x8*)(brow + c * 32);
    bb[c][1] = *(const u16x8*)(brow + c * 32 + 8);
  }

#define ATTN_STEP(BUF, T)                                                      \
  {                                                                            \
    WAITVM_BAR(0);                                                             \
    const char* kb = (const char*)&Ks[BUF][0];                                 \
    const char* vb = (const char*)&Vs[BUF][0];                                 \
    f32x16 sc[4];                                                              \
    __builtin_amdgcn_s_setprio(1);                                             \
    _Pragma("unroll")                                                          \
    for (int c = 0; c < 4; c++) {                                              \
      f32x16 z;                                                                \
      _Pragma("unroll")                                                        \
      for (int r = 0; r < 8; r++)                                              \
        z[r] = __uint_as_float((unsigned)bb[c][0][r] << 16);                   \
      _Pragma("unroll")                                                        \
      for (int r = 0; r < 8; r++)                                              \
        z[8 + r] = __uint_as_float((unsigned)bb[c][1][r] << 16);               \
      const int rowb = (c * 32 + l31) * 128;                                   \
      _Pragma("unroll")                                                        \
      for (int dc = 0; dc < 4; dc++) {                                         \
        bf16x8 ak =                                                            \
            *(const bf16x8*)(kb + rowb + ((dc * 32 + hi2 * 16) ^ kx));         \
        z = MFMA32(ak, bq[dc], z);                                             \
      }                                                                        \
      sc[c] = z;                                                               \
    }                                                                          \
    __builtin_amdgcn_s_setprio(0);                                             \
    const int nkv = (((T) + 1) & 15) * 128;                                    \
    _Pragma("unroll")                                                          \
    for (int i = 0; i < 4; i++)                                                \
      GLD16(Kg + (size_t)(nkv + rK[i]) * 64 + cK[i] * 8,                       \
            &Ks[(BUF) ^ 1][ldd[i]]);                                           \
    _Pragma("unroll")                                                          \
    for (int i = 0; i < 4; i++)                                                \
      GLD16(Vg + (size_t)rV[i] * 2048 + nkv + cV[i] * 8,                       \
            &Vs[(BUF) ^ 1][ldd[i]]);                                           \
    _Pragma("unroll")                                                          \
    for (int c = 0; c < 4; c++) {                                              \
      bb[c][0] = *(const u16x8*)(brow + nkv + c * 32);                         \
      bb[c][1] = *(const u16x8*)(brow + nkv + c * 32 + 8);                     \
    }                                                                          \
    _Pragma("unroll")                                                          \
    for (int c = 0; c < 4; c++)                                                \
      _Pragma("unroll")                                                        \
      for (int r = 0; r < 16; r++) sc[c][r] = EXP2(sc[c][r]);                  \
    float cs[4];                                                               \
    _Pragma("unroll")                                                          \
    for (int c = 0; c < 4; c++) {                                              \
      float s8[8];                                                             \
      _Pragma("unroll")                                                        \
      for (int r = 0; r < 8; r++) s8[r] = sc[c][r] + sc[c][r + 8];             \
      float s4[4];                                                             \
      _Pragma("unroll")                                                        \
      for (int r = 0; r < 4; r++) s4[r] = s8[r] + s8[r + 4];                   \
      cs[c] = (s4[0] + s4[1]) + (s4[2] + s4[3]);                               \
    }                                                                          \
    lrun += (cs[0] + cs[1]) + (cs[2] + cs[3]);                                 \
    __builtin_amdgcn_s_setprio(1);                                             \
    _Pragma("unroll")                                                          \
    for (int c = 0; c < 4; c++) {                                              \
      unsigned a0 = pkc(sc[c][0], sc[c][1]), b0 = pkc(sc[c][4], sc[c][5]);     \
      unsigned a1 = pkc(sc[c][2], sc[c][3]), b1 = pkc(sc[c][6], sc[c][7]);     \
      unsigned e0 = pkc(sc[c][8], sc[c][9]), f0 = pkc(sc[c][12], sc[c][13]);   \
      unsigned e1 = pkc(sc[c][10], sc[c][11]), f1 = pkc(sc[c][14], sc[c][15]); \
      pl32swap(a0, b0); pl32swap(a1, b1);                                      \
      pl32swap(e0, f0); pl32swap(e1, f1);                                      \
      union { unsigned u[4]; bf16x8 v; } fe, fo;                               \
      fe.u[0] = a0; fe.u[1] = a1; fe.u[2] = b0; fe.u[3] = b1;                  \
      fo.u[0] = e0; fo.u[1] = e1; fo.u[2] = f0; fo.u[3] = f1;                  \
      _Pragma("unroll")                                                        \
      for (int ds = 0; ds < 2; ds++) {                                         \
        const int vrow = (ds * 32 + l31) * 256;                                \
        bf16x8 ve =                                                            \
            *(const bf16x8*)(vb + vrow + (((c * 4 + hi2) * 16) ^ kx));         \
        acc[ds] = MFMA32(ve, fe.v, acc[ds]);                                   \
        bf16x8 vo =                                                            \
            *(const bf16x8*)(vb + vrow + (((c * 4 + 2 + hi2) * 16) ^ kx));     \
        acc[ds] = MFMA32(vo, fo.v, acc[ds]);                                   \
      }                                                                        \
    }                                                                          \
    __builtin_amdgcn_s_setprio(0);                                             \
  }

  for (int t = 0; t < 16; t += 2) {
    ATTN_STEP(0, t)
    ATTN_STEP(1, t + 1)
  }
#undef ATTN_STEP

  lrun += __shfl_xor(lrun, 32, 64);
  float linv = 1.0f / lrun;
  const size_t obase =
      ((size_t)b * 2048 + q0 + w * 32 + l31) * 1024 + h * 64 + hi2 * 4;
#pragma unroll
  for (int ds = 0; ds < 2; ds++)
#pragma unroll
    for (int t = 0; t < 4; t++) {
      u16x4 pk;
#pragma unroll
      for (int j = 0; j < 4; j++) pk[j] = f2bf(acc[ds][t * 4 + j] * linv);
      *(u16x4*)(Ob + obase + ds * 32 + t * 8) = pk;
    }
}

// ---------------------------------------------------------------------------
extern "C" void kernel_launch(void* const* d_in, const int* in_sizes, int n_in,
                              void* d_out, int out_size, void* d_ws,
                              size_t ws_size, hipStream_t stream) {
  (void)in_sizes; (void)n_in; (void)out_size;
  const float* q_in = (const float*)d_in[0];
  const float* k_in = (const float*)d_in[1];
  const float* v_in = (const float*)d_in[2];
  const int* mask = (const int*)d_in[3];
  const float* attn_bias = (const float*)d_in[4];
  const float* w_q = (const float*)d_in[5];
  const float* b_q = (const float*)d_in[6];
  const float* w_k = (const float*)d_in[7];
  const float* b_k = (const float*)d_in[8];
  const float* w_v = (const float*)d_in[9];
  const float* b_v = (const float*)d_in[10];
  const float* w_o = (const float*)d_in[11];
  const float* b_o = (const float*)d_in[12];

  const size_t MB = 1u << 20;
  char* ws = (char*)d_ws;
  u16* XQ = (u16*)(ws + 0 * MB);
  u16* XK = (u16*)(ws + 8 * MB);
  u16* XV = (u16*)(ws + 16 * MB);
  u16* WQ = (u16*)(ws + 24 * MB);
  u16* WK = (u16*)(ws + 26 * MB);
  u16* WV = (u16*)(ws + 28 * MB);
  u16* WO = (u16*)(ws + 30 * MB);
  u16* Qb = (u16*)(ws + 32 * MB);
  u16* Kb = (u16*)(ws + 40 * MB);
  u16* Vt = (u16*)(ws + 48 * MB);
  u16* Ob = (u16*)(ws + 56 * MB);
  const bool merged = ws_size >= (size_t)80 * MB;
  u16* BiasE = (u16*)(ws + (merged ? 64 : 0) * MB);

  ConvArgs ca;
  ca.d[0] = {q_in, XQ, 4096 * 1024};
  ca.d[1] = {k_in, XK, 4096 * 1024};
  ca.d[2] = {v_in, XV, 4096 * 1024};
  ca.d[3] = {w_q, WQ, 1024 * 1024};
  ca.d[4] = {w_k, WK, 1024 * 1024};
  ca.d[5] = {w_v, WV, 1024 * 1024};
  ca.d[6] = {w_o, WO, 1024 * 1024};
  k_prep<<<dim3(2048, merged ? 8 : 7), 256, 0, stream>>>(ca, attn_bias, mask,
                                                         BiasE);

  const float QSCALE = 0.125f * 1.44269504f;
  Gemm3 g3;
  g3.d[0] = {XQ, WQ, b_q, (void*)Qb, 0, QSCALE};
  g3.d[1] = {XK, WK, b_k, (void*)Kb, 0, 1.0f};
  g3.d[2] = {XV, WV, b_v, (void*)Vt, 1, 1.0f};
  k_gemm_qkv<<<768, 256, 0, stream>>>(g3);

  if (!merged) k_biasprep<<<2048, 256, 0, stream>>>(attn_bias, mask, BiasE);

  k_attn<<<512, 256, 0, stream>>>(Qb, Kb, Vt, BiasE, Ob);

  k_gemm_o<<<512, 256, 0, stream>>>(Ob, WO, b_o, (float*)d_out);
}